// Round 6
// baseline (278.817 us; speedup 1.0000x reference)
//
#include <hip/hip_runtime.h>
#include <hip/hip_bf16.h>

// ---------------------------------------------------------------------------
// 2-layer GCN, atomic-free CSC gather, bf16 payloads + bf16 MFMA GEMMs.
// dis[] is folded into the gathered payloads (xb = x*dis, zb = z*dis), so
// edge records are source-index-only (4 B). Aggregation at target c:
//   A·v|_c = dis[c] * (sum_r payload[r] + payload[c])
// Layer 1: h = relu((A x) @ W1 + b1)   [reassociated]
// Layer 2: out = A (h @ W2) + b2
//
// R1: LDS-aggregated bucket histogram replaces 1.6M global atomics.
// R3: gather1 at compulsory-miss floor (FETCH ~ 8 XCD x 22 MB distinct
// sources = 93% of 190 MB); GEMM1+GEMM2 fused (k_gemm12).
// R5: build chain widened (fill2 1024 thr, binfill/bcount 512 thr).
// R6: zb pitch padded 80->128 B (each random gather2 row = exactly one
// aligned cache line; fetch ~144->~89 MB). x->xb conversion folded into
// k_fill2 (uses bucket-local dis, overlaps under atomic latency); W
// conversions ride on the k_bscan launch. 9 -> 8 dispatches.
// ---------------------------------------------------------------------------

#define FB_SHIFT 9              // 512 nodes per bucket; r<2^17 packs with c_local

__device__ __forceinline__ unsigned bf16rn(float f) {
    unsigned x = __float_as_uint(f);
    unsigned r = ((x >> 16) & 1u) + 0x7fffu;   // RNE
    return (x + r) >> 16;
}
__device__ __forceinline__ float bf_lo(unsigned u) { return __uint_as_float(u << 16); }
__device__ __forceinline__ float bf_hi(unsigned u) { return __uint_as_float(u & 0xffff0000u); }

typedef __bf16 bf16x8 __attribute__((ext_vector_type(8)));
typedef float  f32x4  __attribute__((ext_vector_type(4)));

// ---- bucket histogram: LDS-aggregated, ~256 global atomics per block ------
__global__ __launch_bounds__(512) void k_bcount(const int* __restrict__ col,
                                                int* __restrict__ btot, int E) {
    __shared__ int h[256];
    const int tid = threadIdx.x;
    if (tid < 256) h[tid] = 0;
    __syncthreads();
    const int base = blockIdx.x * 4096;
#pragma unroll
    for (int k = 0; k < 8; ++k) {
        int e = base + k * 512 + tid;
        if (e < E) atomicAdd(&h[col[e] >> FB_SHIFT], 1);
    }
    __syncthreads();
    if (tid < 256) {
        int v = h[tid];
        if (v > 0) atomicAdd(&btot[tid], v);
    }
}

// ---- block 0: scan 256 bucket totals -> bbase/bcur; blocks 1+: W cvt ------
__global__ __launch_bounds__(256) void k_bscanw(const int* __restrict__ btot,
                                                int* __restrict__ bbase,
                                                int* __restrict__ bcur,
                                                const float* __restrict__ W1,
                                                const float* __restrict__ W2,
                                                unsigned* __restrict__ Wt,
                                                unsigned* __restrict__ W2t) {
    const int t = threadIdx.x;
    if (blockIdx.x == 0) {
        __shared__ int s[256];
        int v = btot[t];            // btot zeroed beyond nbuck, all 256 valid
        s[t] = v;
        __syncthreads();
#pragma unroll
        for (int off = 1; off < 256; off <<= 1) {
            int u = (t >= off) ? s[t - off] : 0;
            __syncthreads();
            s[t] += u;
            __syncthreads();
        }
        int excl = s[t] - v;
        bbase[t] = excl;
        bcur[t] = excl;
        if (t == 255) bbase[256] = s[255];
        return;
    }
    int w = (blockIdx.x - 1) * 256 + t;    // 0..11263
    if (w < 8192) {
        int n = w >> 6, kk = (w & 63) * 2;
        unsigned lo = bf16rn(W1[(size_t)kk * 128 + n]);
        unsigned hi = bf16rn(W1[(size_t)(kk + 1) * 128 + n]);
        Wt[w] = lo | (hi << 16);
    } else if (w < 8192 + 3072) {
        int u = w - 8192;
        int n = u >> 6, kk = (u & 63) * 2;
        unsigned lo = 0, hi = 0;
        if (n < 40) {
            lo = bf16rn(W2[(size_t)kk * 40 + n]);
            hi = bf16rn(W2[(size_t)(kk + 1) * 40 + n]);
        }
        W2t[u] = lo | (hi << 16);
    }
}

// ---- multisplit pass A: bin edges by target bucket, packed (r<<9|c_local) -
__global__ __launch_bounds__(512) void k_binfill(const int* __restrict__ row,
                                                 const int* __restrict__ col,
                                                 int* __restrict__ bcur,
                                                 unsigned* __restrict__ bins, int E) {
    __shared__ int hist[256];
    __shared__ int scn[256];
    __shared__ int gbase[256];
    __shared__ int rcnt[256];
    __shared__ unsigned stage[4096];
    __shared__ unsigned char bkts[4096];

    const int tid = threadIdx.x;
    const int base = blockIdx.x * 4096;

    if (tid < 256) { hist[tid] = 0; rcnt[tid] = 0; }
    __syncthreads();

    unsigned mypk[8];
    int      myb[8];
#pragma unroll
    for (int k = 0; k < 8; ++k) {
        int e = base + k * 512 + tid;
        if (e < E) {
            int r = row[e], c = col[e];
            int b = c >> FB_SHIFT;
            mypk[k] = ((unsigned)r << FB_SHIFT) | (unsigned)(c & ((1 << FB_SHIFT) - 1));
            myb[k] = b;
            atomicAdd(&hist[b], 1);
        } else {
            myb[k] = -1;
        }
    }
    __syncthreads();

    int v = 0;
    if (tid < 256) { v = hist[tid]; scn[tid] = v; }
    __syncthreads();
#pragma unroll
    for (int off = 1; off < 256; off <<= 1) {
        int t = (tid >= off && tid < 256) ? scn[tid - off] : 0;
        __syncthreads();
        if (tid < 256) scn[tid] += t;
        __syncthreads();
    }
    if (tid < 256) {
        int excl = scn[tid] - v;
        scn[tid] = excl;
    }
    __syncthreads();

#pragma unroll
    for (int k = 0; k < 8; ++k) {
        int b = myb[k];
        if (b >= 0) {
            int slot = scn[b] + atomicAdd(&rcnt[b], 1);
            stage[slot] = mypk[k];
            bkts[slot] = (unsigned char)b;
        }
    }

    if (tid < 256 && hist[tid] > 0) gbase[tid] = atomicAdd(&bcur[tid], hist[tid]);
    __syncthreads();

    int total = scn[255] + hist[255];
    for (int s = tid; s < total; s += 512) {
        unsigned u = stage[s];
        int b = bkts[s];
        bins[gbase[b] + (s - scn[b])] = u;
    }
}

// ---- multisplit pass B: degree count + scan + scatter + xb conversion -----
__global__ __launch_bounds__(1024) void k_fill2(const unsigned* __restrict__ bins,
                                                const int* __restrict__ bbase,
                                                int* __restrict__ rowptr,
                                                float* __restrict__ dis,
                                                int* __restrict__ pair,
                                                const float* __restrict__ x,
                                                unsigned* __restrict__ xb, int N) {
    __shared__ int cnt[512];
    __shared__ int lcur[512];
    __shared__ int ssum[256];
    __shared__ float ldisv[512];
    const int tid = threadIdx.x;
    const int b = blockIdx.x;
    const int n0 = b << FB_SHIFT;
    const int start = bbase[b];
    const int end = bbase[b + 1];

    if (tid < 512) cnt[tid] = 0;
    __syncthreads();

    for (int i = start + tid; i < end; i += 1024)
        atomicAdd(&cnt[bins[i] & ((1 << FB_SHIFT) - 1)], 1);
    __syncthreads();

    int c0 = 0, c1 = 0, vsum = 0;
    if (tid < 256) {
        c0 = cnt[2 * tid]; c1 = cnt[2 * tid + 1];
        vsum = c0 + c1;
        ssum[tid] = vsum;
    }
    __syncthreads();
#pragma unroll
    for (int off = 1; off < 256; off <<= 1) {
        int u = (tid >= off && tid < 256) ? ssum[tid - off] : 0;
        __syncthreads();
        if (tid < 256) ssum[tid] += u;
        __syncthreads();
    }
    if (tid < 256) {
        int e0 = start + ssum[tid] - vsum;
        int e1 = e0 + c0;
        lcur[2 * tid] = e0;
        lcur[2 * tid + 1] = e1;
        int node0 = n0 + 2 * tid;
        int node1 = node0 + 1;
        float d0 = rsqrtf((float)(c0 + 1));   // +1 self-loop
        float d1 = rsqrtf((float)(c1 + 1));
        ldisv[2 * tid] = d0;
        ldisv[2 * tid + 1] = d1;
        if (node0 <= N) rowptr[node0] = e0;
        if (node1 <= N) rowptr[node1] = e1;
        if (node0 < N) dis[node0] = d0;
        if (node1 < N) dis[node1] = d1;
    }
    __syncthreads();

    for (int i = start + tid; i < end; i += 1024) {
        unsigned u = bins[i];
        int pos = atomicAdd(&lcur[u & ((1 << FB_SHIFT) - 1)], 1);
        pair[pos] = (int)(u >> FB_SHIFT);
    }

    // xb conversion for this bucket's rows: xb = bf16x2(x * dis)
    // 32 threads per row (32 float4 segs), 32 rows in flight, 16 passes.
    int nrows = N - n0; if (nrows > 512) nrows = 512;
    int rloc = tid >> 5;
    int cseg = tid & 31;
    for (int rr = rloc; rr < nrows; rr += 32) {
        int node = n0 + rr;
        float d = ldisv[rr];
        float4 v = ((const float4*)(x + (size_t)node * 128))[cseg];
        uint2 o;
        o.x = bf16rn(v.x * d) | (bf16rn(v.y * d) << 16);
        o.y = bf16rn(v.z * d) | (bf16rn(v.w * d) << 16);
        ((uint2*)(xb + (size_t)node * 64))[cseg] = o;
    }
}

// ---- gather layer 1: xab[c] = bf16(dis[c] * (sum_r xb[r] + xb[c])) --------
// Wave per node; index-only pair records; 8 gathers in flight. At the
// compulsory-miss floor (FETCH ~ 8 XCD x 22 MB distinct source rows).
__global__ __launch_bounds__(256) void k_gather1(const unsigned* __restrict__ xb,
                                                 const int* __restrict__ rowptr,
                                                 const int* __restrict__ pair,
                                                 const float* __restrict__ dis,
                                                 unsigned* __restrict__ xab, int N) {
    int gw = (blockIdx.x * 256 + threadIdx.x) >> 6;
    int lane = threadIdx.x & 63;
    if (gw >= N) return;
    float dv = dis[gw];
    unsigned us = xb[(size_t)gw * 64 + lane];
    float2 acc = make_float2(bf_lo(us), bf_hi(us));   // self term (rows pre-scaled)
    int j = rowptr[gw], je = rowptr[gw + 1];

    for (; j + 7 < je; j += 8) {
        int r0 = pair[j],     r1 = pair[j + 1], r2 = pair[j + 2], r3 = pair[j + 3];
        int r4 = pair[j + 4], r5 = pair[j + 5], r6 = pair[j + 6], r7 = pair[j + 7];
        unsigned a0 = xb[(size_t)r0 * 64 + lane];
        unsigned a1 = xb[(size_t)r1 * 64 + lane];
        unsigned a2 = xb[(size_t)r2 * 64 + lane];
        unsigned a3 = xb[(size_t)r3 * 64 + lane];
        unsigned a4 = xb[(size_t)r4 * 64 + lane];
        unsigned a5 = xb[(size_t)r5 * 64 + lane];
        unsigned a6 = xb[(size_t)r6 * 64 + lane];
        unsigned a7 = xb[(size_t)r7 * 64 + lane];
        acc.x += bf_lo(a0); acc.y += bf_hi(a0);
        acc.x += bf_lo(a1); acc.y += bf_hi(a1);
        acc.x += bf_lo(a2); acc.y += bf_hi(a2);
        acc.x += bf_lo(a3); acc.y += bf_hi(a3);
        acc.x += bf_lo(a4); acc.y += bf_hi(a4);
        acc.x += bf_lo(a5); acc.y += bf_hi(a5);
        acc.x += bf_lo(a6); acc.y += bf_hi(a6);
        acc.x += bf_lo(a7); acc.y += bf_hi(a7);
    }
    for (; j + 3 < je; j += 4) {
        int r0 = pair[j], r1 = pair[j + 1], r2 = pair[j + 2], r3 = pair[j + 3];
        unsigned a0 = xb[(size_t)r0 * 64 + lane];
        unsigned a1 = xb[(size_t)r1 * 64 + lane];
        unsigned a2 = xb[(size_t)r2 * 64 + lane];
        unsigned a3 = xb[(size_t)r3 * 64 + lane];
        acc.x += bf_lo(a0); acc.y += bf_hi(a0);
        acc.x += bf_lo(a1); acc.y += bf_hi(a1);
        acc.x += bf_lo(a2); acc.y += bf_hi(a2);
        acc.x += bf_lo(a3); acc.y += bf_hi(a3);
    }
    for (; j < je; ++j) {
        unsigned a0 = xb[(size_t)pair[j] * 64 + lane];
        acc.x += bf_lo(a0); acc.y += bf_hi(a0);
    }
    xab[(size_t)gw * 64 + lane] = bf16rn(dv * acc.x) | (bf16rn(dv * acc.y) << 16);
}

// ---- fused GEMM1+GEMM2 (MFMA bf16) ----------------------------------------
// h = relu(xab @ W1t^T + b1)  (h kept in LDS, never hits global)
// Zb[M, pitch 32] = bf16( (h @ W2t^T) * dis[row] )  (20 uints used, 12 pad)
__global__ __launch_bounds__(256) void k_gemm12(const unsigned* __restrict__ Ab,
                                                const unsigned* __restrict__ Wt,
                                                const unsigned* __restrict__ W2t,
                                                const float* __restrict__ bias,
                                                const float* __restrict__ dis,
                                                unsigned* __restrict__ Zb, int M) {
    __shared__ char smem[70144];            // 34816 + 34816 + 512 (ldis)
    char* Abase = smem;
    char* Bbase = smem + 34816;
    float* ldis = (float*)(smem + 69632);

    const int tid = threadIdx.x;
    const int r0 = blockIdx.x * 128;

#pragma unroll
    for (int s = 0; s < 8; ++s) {
        int l = tid + s * 256;
        int row = l >> 4, q = l & 15;
        uint4 va = *(const uint4*)(Ab + (size_t)(r0 + row) * 64 + q * 4);
        *(uint4*)(Abase + row * 272 + q * 16) = va;
        uint4 vb = *(const uint4*)(Wt + (size_t)row * 64 + q * 4);
        *(uint4*)(Bbase + row * 272 + q * 16) = vb;
    }
    if (tid < 128) {
        int rr = r0 + tid;
        ldis[tid] = (rr < M) ? dis[rr] : 0.f;
    }
    __syncthreads();

    const int wv = tid >> 6, lane = tid & 63;
    const int quad = lane >> 4, mcol = lane & 15;

    // ---------------- GEMM1: acc1 = xab @ W1t^T ----------------
    f32x4 acc1[2][8];
#pragma unroll
    for (int rt = 0; rt < 2; ++rt)
#pragma unroll
        for (int ct = 0; ct < 8; ++ct) acc1[rt][ct] = (f32x4){0.f, 0.f, 0.f, 0.f};

#pragma unroll
    for (int ks = 0; ks < 4; ++ks) {
        bf16x8 a[2], b[8];
#pragma unroll
        for (int rt = 0; rt < 2; ++rt) {
            int row = wv * 32 + rt * 16 + mcol;
            a[rt] = *(const bf16x8*)(Abase + row * 272 + ks * 64 + quad * 16);
        }
#pragma unroll
        for (int ct = 0; ct < 8; ++ct) {
            int n = ct * 16 + mcol;
            b[ct] = *(const bf16x8*)(Bbase + n * 272 + ks * 64 + quad * 16);
        }
#pragma unroll
        for (int rt = 0; rt < 2; ++rt)
#pragma unroll
            for (int ct = 0; ct < 8; ++ct)
                acc1[rt][ct] = __builtin_amdgcn_mfma_f32_16x16x32_bf16(
                    a[rt], b[ct], acc1[rt][ct], 0, 0, 0);
    }
    __syncthreads();     // all waves done reading As (xab) and Bs (W1)

    // h (relu + bias, bf16) -> Bs region; W2 tile -> As region
    unsigned short* Hs = (unsigned short*)Bbase;     // pitch 136 ushorts
#pragma unroll
    for (int rt = 0; rt < 2; ++rt)
#pragma unroll
        for (int ct = 0; ct < 8; ++ct) {
            float bb = bias[ct * 16 + mcol];
#pragma unroll
            for (int r = 0; r < 4; ++r) {
                float v = acc1[rt][ct][r] + bb;
                v = v > 0.f ? v : 0.f;
                int orow = wv * 32 + rt * 16 + quad * 4 + r;
                Hs[orow * 136 + ct * 16 + mcol] = (unsigned short)bf16rn(v);
            }
        }
#pragma unroll
    for (int s = 0; s < 3; ++s) {
        int l = tid + s * 256;
        int row = l >> 4, q = l & 15;
        uint4 vb = *(const uint4*)(W2t + (size_t)row * 64 + q * 4);
        *(uint4*)(Abase + row * 272 + q * 16) = vb;
    }
    __syncthreads();

    // ---------------- GEMM2: acc2 = h @ W2t^T ----------------
    f32x4 acc2[2][3];
#pragma unroll
    for (int rt = 0; rt < 2; ++rt)
#pragma unroll
        for (int ct = 0; ct < 3; ++ct) acc2[rt][ct] = (f32x4){0.f, 0.f, 0.f, 0.f};

#pragma unroll
    for (int ks = 0; ks < 4; ++ks) {
        bf16x8 a[2], b[3];
#pragma unroll
        for (int rt = 0; rt < 2; ++rt) {
            int row = wv * 32 + rt * 16 + mcol;
            a[rt] = *(const bf16x8*)(Bbase + row * 272 + ks * 64 + quad * 16);
        }
#pragma unroll
        for (int ct = 0; ct < 3; ++ct) {
            int n = ct * 16 + mcol;
            b[ct] = *(const bf16x8*)(Abase + n * 272 + ks * 64 + quad * 16);
        }
#pragma unroll
        for (int rt = 0; rt < 2; ++rt)
#pragma unroll
            for (int ct = 0; ct < 3; ++ct)
                acc2[rt][ct] = __builtin_amdgcn_mfma_f32_16x16x32_bf16(
                    a[rt], b[ct], acc2[rt][ct], 0, 0, 0);
    }
    __syncthreads();

    // epilogue: scale by dis[row], pack bf16 rows at 56-ushort pitch (112 B)
    unsigned short* Zs = (unsigned short*)(Abase + 16384);  // above W2 (13056 B)
#pragma unroll
    for (int rt = 0; rt < 2; ++rt)
#pragma unroll
        for (int ct = 0; ct < 3; ++ct) {
#pragma unroll
            for (int r = 0; r < 4; ++r) {
                int orow = wv * 32 + rt * 16 + quad * 4 + r;
                float v = acc2[rt][ct][r] * ldis[orow];
                Zs[orow * 56 + ct * 16 + mcol] = (unsigned short)bf16rn(v);
            }
        }
    __syncthreads();

    if (tid < 128) {
        int rr = r0 + tid;
        if (rr < M) {
            const uint4* s4 = (const uint4*)(Abase + 16384 + tid * 112);
            uint4* d4 = (uint4*)(Zb + ((size_t)rr << 5));   // pitch 32 uints
#pragma unroll
            for (int q = 0; q < 5; ++q) d4[q] = s4[q];
        }
    }
}

// ---- gather layer 2: out[c] = b2 + dis[c] * (sum_r zb[r] + zb[c]) ---------
// Half-wave per edge stream; 16 edges in flight (8 per half).
// zb pitch = 32 uints (128 B): one aligned cache line per random row.
__global__ __launch_bounds__(256) void k_gather2(const unsigned* __restrict__ zb,
                                                 const int* __restrict__ rowptr,
                                                 const int* __restrict__ pair,
                                                 const float* __restrict__ dis,
                                                 const float* __restrict__ b2,
                                                 float* __restrict__ out, int N) {
    int gw = (blockIdx.x * 256 + threadIdx.x) >> 6;
    int lane = threadIdx.x & 63;
    if (gw >= N) return;
    int sub = lane >> 5;
    int sl  = lane & 31;
    int f   = (sl < 20) ? sl : 19;

    float2 acc = make_float2(0.f, 0.f);
    float dv = dis[gw];
    if (sub == 0) {                       // self term (rows pre-scaled by dis)
        unsigned u = zb[((size_t)gw << 5) + f];
        acc.x = bf_lo(u); acc.y = bf_hi(u);
    }

    int j = rowptr[gw], je = rowptr[gw + 1];
    for (; j + 15 < je; j += 16) {
        int rA = pair[j + sub];
        int rB = pair[j + 2 + sub];
        int rC = pair[j + 4 + sub];
        int rD = pair[j + 6 + sub];
        int rE = pair[j + 8 + sub];
        int rF = pair[j + 10 + sub];
        int rG = pair[j + 12 + sub];
        int rH = pair[j + 14 + sub];
        unsigned uA = zb[((size_t)rA << 5) + f];
        unsigned uB = zb[((size_t)rB << 5) + f];
        unsigned uC = zb[((size_t)rC << 5) + f];
        unsigned uD = zb[((size_t)rD << 5) + f];
        unsigned uE = zb[((size_t)rE << 5) + f];
        unsigned uF = zb[((size_t)rF << 5) + f];
        unsigned uG = zb[((size_t)rG << 5) + f];
        unsigned uH = zb[((size_t)rH << 5) + f];
        acc.x += bf_lo(uA); acc.y += bf_hi(uA);
        acc.x += bf_lo(uB); acc.y += bf_hi(uB);
        acc.x += bf_lo(uC); acc.y += bf_hi(uC);
        acc.x += bf_lo(uD); acc.y += bf_hi(uD);
        acc.x += bf_lo(uE); acc.y += bf_hi(uE);
        acc.x += bf_lo(uF); acc.y += bf_hi(uF);
        acc.x += bf_lo(uG); acc.y += bf_hi(uG);
        acc.x += bf_lo(uH); acc.y += bf_hi(uH);
    }
    for (; j + 7 < je; j += 8) {
        int rA = pair[j + sub];
        int rB = pair[j + 2 + sub];
        int rC = pair[j + 4 + sub];
        int rD = pair[j + 6 + sub];
        unsigned uA = zb[((size_t)rA << 5) + f];
        unsigned uB = zb[((size_t)rB << 5) + f];
        unsigned uC = zb[((size_t)rC << 5) + f];
        unsigned uD = zb[((size_t)rD << 5) + f];
        acc.x += bf_lo(uA); acc.y += bf_hi(uA);
        acc.x += bf_lo(uB); acc.y += bf_hi(uB);
        acc.x += bf_lo(uC); acc.y += bf_hi(uC);
        acc.x += bf_lo(uD); acc.y += bf_hi(uD);
    }
    for (; j + 3 < je; j += 4) {
        int rA = pair[j + sub];
        int rB = pair[j + 2 + sub];
        unsigned uA = zb[((size_t)rA << 5) + f];
        unsigned uB = zb[((size_t)rB << 5) + f];
        acc.x += bf_lo(uA); acc.y += bf_hi(uA);
        acc.x += bf_lo(uB); acc.y += bf_hi(uB);
    }
    for (; j + 1 < je; j += 2) {
        unsigned u = zb[((size_t)pair[j + sub] << 5) + f];
        acc.x += bf_lo(u); acc.y += bf_hi(u);
    }
    if (j < je && sub == 0) {
        unsigned u = zb[((size_t)pair[j] << 5) + f];
        acc.x += bf_lo(u); acc.y += bf_hi(u);
    }

    float bx = __shfl(acc.x, sl + 32, 64);
    float by = __shfl(acc.y, sl + 32, 64);
    if (sub == 0 && sl < 20) {
        float2 bias = ((const float2*)b2)[sl];
        float2 res = make_float2((acc.x + bx) * dv + bias.x,
                                 (acc.y + by) * dv + bias.y);
        ((float2*)(out + (size_t)gw * 40))[sl] = res;
    }
}

// ---------------------------------------------------------------------------
extern "C" void kernel_launch(void* const* d_in, const int* in_sizes, int n_in,
                              void* d_out, int out_size, void* d_ws, size_t ws_size,
                              hipStream_t stream) {
    const float* x  = (const float*)d_in[0];
    const int*   ei = (const int*)d_in[1];
    const float* W1 = (const float*)d_in[2];
    const float* b1 = (const float*)d_in[3];
    const float* W2 = (const float*)d_in[4];
    const float* b2 = (const float*)d_in[5];
    float* out = (float*)d_out;

    const int N = in_sizes[0] / 128;
    const int E = in_sizes[1] / 2;
    const int* row = ei;        // sources
    const int* col = ei + E;    // targets

    const int Np = (N + 255) & ~255;
    const int nbuck = (N + (1 << FB_SHIFT) - 1) >> FB_SHIFT;   // <= 256

    // workspace layout (4-byte units)
    int*      rowptr = (int*)d_ws;                       // Np + 256
    int*      btot   = rowptr + Np + 256;                // 256
    int*      bbase  = btot + 256;                       // 320 (257 used)
    int*      bcur   = bbase + 320;                      // 256
    float*    dis    = (float*)(bcur + 256);             // Np
    unsigned* Wt     = (unsigned*)(dis + Np);            // 8192 (W1t bf16)
    unsigned* W2t    = Wt + 8192;                        // 3072 (W2t bf16, 48 rows)
    int*      pair   = (int*)(W2t + 3072);               // E ints (src index only)
    unsigned* xb     = (unsigned*)(pair + E);            // N*64 (bf16 x*dis)
    unsigned* xab    = xb + (size_t)N * 64;              // N*64 (bf16 A*x)
    unsigned* zb     = xab + (size_t)N * 64;             // N*32 (bf16 z*dis, padded)
    unsigned* bins   = (unsigned*)xab;  // alias: dead before k_gather1 writes xab

    // bucket histogram -> bucket scan (+W cvt) -> CSC build (+xb cvt)
    hipMemsetAsync(btot, 0, 256 * sizeof(int), stream);
    k_bcount<<<(E + 4095) / 4096, 512, 0, stream>>>(col, btot, E);
    k_bscanw<<<45, 256, 0, stream>>>(btot, bbase, bcur, W1, W2, Wt, W2t);
    k_binfill<<<(E + 4095) / 4096, 512, 0, stream>>>(row, col, bcur, bins, E);
    k_fill2<<<nbuck, 1024, 0, stream>>>(bins, bbase, rowptr, dis, pair, x, xb, N);

    // layer 1 gather: xab = bf16(A x)
    k_gather1<<<(N + 3) / 4, 256, 0, stream>>>(xb, rowptr, pair, dis, xab, N);

    // fused GEMMs: zb = bf16((relu(xab@W1+b1) @ W2) * dis)   [MFMA]
    k_gemm12<<<(N + 127) / 128, 256, 0, stream>>>(xab, Wt, W2t, b1, dis, zb, N);

    // layer 2 gather: out = b2 + dis*(sum zb)
    k_gather2<<<(N + 3) / 4, 256, 0, stream>>>(zb, rowptr, pair, dis, b2, out, N);
}

// Round 7
// 273.054 us; speedup vs baseline: 1.0211x; 1.0211x over previous
//
#include <hip/hip_runtime.h>
#include <hip/hip_bf16.h>

// ---------------------------------------------------------------------------
// 2-layer GCN, atomic-free CSC gather, bf16 payloads + bf16 MFMA GEMMs.
// dis[] is folded into the gathered payloads (xb = x*dis, zb = z*dis), so
// edge records are source-index-only (4 B). Aggregation at target c:
//   A·v|_c = dis[c] * (sum_r payload[r] + payload[c])
// Layer 1: h = relu((A x) @ W1 + b1)   [reassociated]
// Layer 2: out = A (h @ W2) + b2
//
// R1: LDS-aggregated bucket histogram replaces 1.6M global atomics.
// R3: gather1 at compulsory-miss floor (FETCH ~ 8 XCD x 22 MB distinct
// sources = 93% of 190 MB); GEMM1+GEMM2 fused (k_gemm12).
// R5: build chain widened (fill2 1024 thr, binfill/bcount 512 thr).
// R6: zb pitch 80->128 B (gather2 row = one aligned line) — kept.
// R7: xb-conversion UN-fused from fill2 (R6 regression: the 103 MB stream
// ran on nbuck=196 blocks < 1/CU, grid-starved, serialized after scatter).
// Back to full-grid k_cvtx; fill2 restored to R5 body.
// ---------------------------------------------------------------------------

#define FB_SHIFT 9              // 512 nodes per bucket; r<2^17 packs with c_local

__device__ __forceinline__ unsigned bf16rn(float f) {
    unsigned x = __float_as_uint(f);
    unsigned r = ((x >> 16) & 1u) + 0x7fffu;   // RNE
    return (x + r) >> 16;
}
__device__ __forceinline__ float bf_lo(unsigned u) { return __uint_as_float(u << 16); }
__device__ __forceinline__ float bf_hi(unsigned u) { return __uint_as_float(u & 0xffff0000u); }

typedef __bf16 bf16x8 __attribute__((ext_vector_type(8)));
typedef float  f32x4  __attribute__((ext_vector_type(4)));

// ---- bucket histogram: LDS-aggregated, ~256 global atomics per block ------
__global__ __launch_bounds__(512) void k_bcount(const int* __restrict__ col,
                                                int* __restrict__ btot, int E) {
    __shared__ int h[256];
    const int tid = threadIdx.x;
    if (tid < 256) h[tid] = 0;
    __syncthreads();
    const int base = blockIdx.x * 4096;
#pragma unroll
    for (int k = 0; k < 8; ++k) {
        int e = base + k * 512 + tid;
        if (e < E) atomicAdd(&h[col[e] >> FB_SHIFT], 1);
    }
    __syncthreads();
    if (tid < 256) {
        int v = h[tid];
        if (v > 0) atomicAdd(&btot[tid], v);
    }
}

// ---- block 0: scan 256 bucket totals -> bbase/bcur; blocks 1+: W cvt ------
__global__ __launch_bounds__(256) void k_bscanw(const int* __restrict__ btot,
                                                int* __restrict__ bbase,
                                                int* __restrict__ bcur,
                                                const float* __restrict__ W1,
                                                const float* __restrict__ W2,
                                                unsigned* __restrict__ Wt,
                                                unsigned* __restrict__ W2t) {
    const int t = threadIdx.x;
    if (blockIdx.x == 0) {
        __shared__ int s[256];
        int v = btot[t];            // btot zeroed beyond nbuck, all 256 valid
        s[t] = v;
        __syncthreads();
#pragma unroll
        for (int off = 1; off < 256; off <<= 1) {
            int u = (t >= off) ? s[t - off] : 0;
            __syncthreads();
            s[t] += u;
            __syncthreads();
        }
        int excl = s[t] - v;
        bbase[t] = excl;
        bcur[t] = excl;
        if (t == 255) bbase[256] = s[255];
        return;
    }
    int w = (blockIdx.x - 1) * 256 + t;    // 0..11263
    if (w < 8192) {
        int n = w >> 6, kk = (w & 63) * 2;
        unsigned lo = bf16rn(W1[(size_t)kk * 128 + n]);
        unsigned hi = bf16rn(W1[(size_t)(kk + 1) * 128 + n]);
        Wt[w] = lo | (hi << 16);
    } else if (w < 8192 + 3072) {
        int u = w - 8192;
        int n = u >> 6, kk = (u & 63) * 2;
        unsigned lo = 0, hi = 0;
        if (n < 40) {
            lo = bf16rn(W2[(size_t)kk * 40 + n]);
            hi = bf16rn(W2[(size_t)(kk + 1) * 40 + n]);
        }
        W2t[u] = lo | (hi << 16);
    }
}

// ---- multisplit pass A: bin edges by target bucket, packed (r<<9|c_local) -
__global__ __launch_bounds__(512) void k_binfill(const int* __restrict__ row,
                                                 const int* __restrict__ col,
                                                 int* __restrict__ bcur,
                                                 unsigned* __restrict__ bins, int E) {
    __shared__ int hist[256];
    __shared__ int scn[256];
    __shared__ int gbase[256];
    __shared__ int rcnt[256];
    __shared__ unsigned stage[4096];
    __shared__ unsigned char bkts[4096];

    const int tid = threadIdx.x;
    const int base = blockIdx.x * 4096;

    if (tid < 256) { hist[tid] = 0; rcnt[tid] = 0; }
    __syncthreads();

    unsigned mypk[8];
    int      myb[8];
#pragma unroll
    for (int k = 0; k < 8; ++k) {
        int e = base + k * 512 + tid;
        if (e < E) {
            int r = row[e], c = col[e];
            int b = c >> FB_SHIFT;
            mypk[k] = ((unsigned)r << FB_SHIFT) | (unsigned)(c & ((1 << FB_SHIFT) - 1));
            myb[k] = b;
            atomicAdd(&hist[b], 1);
        } else {
            myb[k] = -1;
        }
    }
    __syncthreads();

    int v = 0;
    if (tid < 256) { v = hist[tid]; scn[tid] = v; }
    __syncthreads();
#pragma unroll
    for (int off = 1; off < 256; off <<= 1) {
        int t = (tid >= off && tid < 256) ? scn[tid - off] : 0;
        __syncthreads();
        if (tid < 256) scn[tid] += t;
        __syncthreads();
    }
    if (tid < 256) {
        int excl = scn[tid] - v;
        scn[tid] = excl;
    }
    __syncthreads();

#pragma unroll
    for (int k = 0; k < 8; ++k) {
        int b = myb[k];
        if (b >= 0) {
            int slot = scn[b] + atomicAdd(&rcnt[b], 1);
            stage[slot] = mypk[k];
            bkts[slot] = (unsigned char)b;
        }
    }

    if (tid < 256 && hist[tid] > 0) gbase[tid] = atomicAdd(&bcur[tid], hist[tid]);
    __syncthreads();

    int total = scn[255] + hist[255];
    for (int s = tid; s < total; s += 512) {
        unsigned u = stage[s];
        int b = bkts[s];
        bins[gbase[b] + (s - scn[b])] = u;
    }
}

// ---- multisplit pass B: bucket-local degree count + scan + scatter --------
__global__ __launch_bounds__(1024) void k_fill2(const unsigned* __restrict__ bins,
                                                const int* __restrict__ bbase,
                                                int* __restrict__ rowptr,
                                                float* __restrict__ dis,
                                                int* __restrict__ pair, int N) {
    __shared__ int cnt[512];
    __shared__ int lcur[512];
    __shared__ int ssum[256];
    const int tid = threadIdx.x;
    const int b = blockIdx.x;
    const int n0 = b << FB_SHIFT;
    const int start = bbase[b];
    const int end = bbase[b + 1];

    if (tid < 512) cnt[tid] = 0;
    __syncthreads();

    for (int i = start + tid; i < end; i += 1024)
        atomicAdd(&cnt[bins[i] & ((1 << FB_SHIFT) - 1)], 1);
    __syncthreads();

    int c0 = 0, c1 = 0, vsum = 0;
    if (tid < 256) {
        c0 = cnt[2 * tid]; c1 = cnt[2 * tid + 1];
        vsum = c0 + c1;
        ssum[tid] = vsum;
    }
    __syncthreads();
#pragma unroll
    for (int off = 1; off < 256; off <<= 1) {
        int u = (tid >= off && tid < 256) ? ssum[tid - off] : 0;
        __syncthreads();
        if (tid < 256) ssum[tid] += u;
        __syncthreads();
    }
    if (tid < 256) {
        int e0 = start + ssum[tid] - vsum;
        int e1 = e0 + c0;
        lcur[2 * tid] = e0;
        lcur[2 * tid + 1] = e1;
        int node0 = n0 + 2 * tid;
        int node1 = node0 + 1;
        if (node0 <= N) rowptr[node0] = e0;
        if (node1 <= N) rowptr[node1] = e1;
        if (node0 < N) dis[node0] = rsqrtf((float)(c0 + 1));   // +1 self-loop
        if (node1 < N) dis[node1] = rsqrtf((float)(c1 + 1));
    }
    __syncthreads();

    for (int i = start + tid; i < end; i += 1024) {
        unsigned u = bins[i];
        int pos = atomicAdd(&lcur[u & ((1 << FB_SHIFT) - 1)], 1);
        pair[pos] = (int)(u >> FB_SHIFT);
    }
}

// ---- x -> xb = bf16x2(x * dis), full-grid streaming, float4/lane ----------
__global__ __launch_bounds__(256) void k_cvtx(const float* __restrict__ x,
                                              const float* __restrict__ dis,
                                              unsigned* __restrict__ xb, int n32) {
    int i = blockIdx.x * 256 + threadIdx.x;
    if (i >= n32) return;
    float4 v = ((const float4*)x)[i];
    float d = dis[i >> 5];
    uint2 o;
    o.x = bf16rn(v.x * d) | (bf16rn(v.y * d) << 16);
    o.y = bf16rn(v.z * d) | (bf16rn(v.w * d) << 16);
    ((uint2*)xb)[i] = o;
}

// ---- gather layer 1: xab[c] = bf16(dis[c] * (sum_r xb[r] + xb[c])) --------
// Wave per node; index-only pair records; 8 gathers in flight. At the
// compulsory-miss floor (FETCH ~ 8 XCD x 22 MB distinct source rows).
__global__ __launch_bounds__(256) void k_gather1(const unsigned* __restrict__ xb,
                                                 const int* __restrict__ rowptr,
                                                 const int* __restrict__ pair,
                                                 const float* __restrict__ dis,
                                                 unsigned* __restrict__ xab, int N) {
    int gw = (blockIdx.x * 256 + threadIdx.x) >> 6;
    int lane = threadIdx.x & 63;
    if (gw >= N) return;
    float dv = dis[gw];
    unsigned us = xb[(size_t)gw * 64 + lane];
    float2 acc = make_float2(bf_lo(us), bf_hi(us));   // self term (rows pre-scaled)
    int j = rowptr[gw], je = rowptr[gw + 1];

    for (; j + 7 < je; j += 8) {
        int r0 = pair[j],     r1 = pair[j + 1], r2 = pair[j + 2], r3 = pair[j + 3];
        int r4 = pair[j + 4], r5 = pair[j + 5], r6 = pair[j + 6], r7 = pair[j + 7];
        unsigned a0 = xb[(size_t)r0 * 64 + lane];
        unsigned a1 = xb[(size_t)r1 * 64 + lane];
        unsigned a2 = xb[(size_t)r2 * 64 + lane];
        unsigned a3 = xb[(size_t)r3 * 64 + lane];
        unsigned a4 = xb[(size_t)r4 * 64 + lane];
        unsigned a5 = xb[(size_t)r5 * 64 + lane];
        unsigned a6 = xb[(size_t)r6 * 64 + lane];
        unsigned a7 = xb[(size_t)r7 * 64 + lane];
        acc.x += bf_lo(a0); acc.y += bf_hi(a0);
        acc.x += bf_lo(a1); acc.y += bf_hi(a1);
        acc.x += bf_lo(a2); acc.y += bf_hi(a2);
        acc.x += bf_lo(a3); acc.y += bf_hi(a3);
        acc.x += bf_lo(a4); acc.y += bf_hi(a4);
        acc.x += bf_lo(a5); acc.y += bf_hi(a5);
        acc.x += bf_lo(a6); acc.y += bf_hi(a6);
        acc.x += bf_lo(a7); acc.y += bf_hi(a7);
    }
    for (; j + 3 < je; j += 4) {
        int r0 = pair[j], r1 = pair[j + 1], r2 = pair[j + 2], r3 = pair[j + 3];
        unsigned a0 = xb[(size_t)r0 * 64 + lane];
        unsigned a1 = xb[(size_t)r1 * 64 + lane];
        unsigned a2 = xb[(size_t)r2 * 64 + lane];
        unsigned a3 = xb[(size_t)r3 * 64 + lane];
        acc.x += bf_lo(a0); acc.y += bf_hi(a0);
        acc.x += bf_lo(a1); acc.y += bf_hi(a1);
        acc.x += bf_lo(a2); acc.y += bf_hi(a2);
        acc.x += bf_lo(a3); acc.y += bf_hi(a3);
    }
    for (; j < je; ++j) {
        unsigned a0 = xb[(size_t)pair[j] * 64 + lane];
        acc.x += bf_lo(a0); acc.y += bf_hi(a0);
    }
    xab[(size_t)gw * 64 + lane] = bf16rn(dv * acc.x) | (bf16rn(dv * acc.y) << 16);
}

// ---- fused GEMM1+GEMM2 (MFMA bf16) ----------------------------------------
// h = relu(xab @ W1t^T + b1)  (h kept in LDS, never hits global)
// Zb[M, pitch 32] = bf16( (h @ W2t^T) * dis[row] )  (20 uints used, 12 pad)
__global__ __launch_bounds__(256) void k_gemm12(const unsigned* __restrict__ Ab,
                                                const unsigned* __restrict__ Wt,
                                                const unsigned* __restrict__ W2t,
                                                const float* __restrict__ bias,
                                                const float* __restrict__ dis,
                                                unsigned* __restrict__ Zb, int M) {
    __shared__ char smem[70144];            // 34816 + 34816 + 512 (ldis)
    char* Abase = smem;
    char* Bbase = smem + 34816;
    float* ldis = (float*)(smem + 69632);

    const int tid = threadIdx.x;
    const int r0 = blockIdx.x * 128;

#pragma unroll
    for (int s = 0; s < 8; ++s) {
        int l = tid + s * 256;
        int row = l >> 4, q = l & 15;
        uint4 va = *(const uint4*)(Ab + (size_t)(r0 + row) * 64 + q * 4);
        *(uint4*)(Abase + row * 272 + q * 16) = va;
        uint4 vb = *(const uint4*)(Wt + (size_t)row * 64 + q * 4);
        *(uint4*)(Bbase + row * 272 + q * 16) = vb;
    }
    if (tid < 128) {
        int rr = r0 + tid;
        ldis[tid] = (rr < M) ? dis[rr] : 0.f;
    }
    __syncthreads();

    const int wv = tid >> 6, lane = tid & 63;
    const int quad = lane >> 4, mcol = lane & 15;

    // ---------------- GEMM1: acc1 = xab @ W1t^T ----------------
    f32x4 acc1[2][8];
#pragma unroll
    for (int rt = 0; rt < 2; ++rt)
#pragma unroll
        for (int ct = 0; ct < 8; ++ct) acc1[rt][ct] = (f32x4){0.f, 0.f, 0.f, 0.f};

#pragma unroll
    for (int ks = 0; ks < 4; ++ks) {
        bf16x8 a[2], b[8];
#pragma unroll
        for (int rt = 0; rt < 2; ++rt) {
            int row = wv * 32 + rt * 16 + mcol;
            a[rt] = *(const bf16x8*)(Abase + row * 272 + ks * 64 + quad * 16);
        }
#pragma unroll
        for (int ct = 0; ct < 8; ++ct) {
            int n = ct * 16 + mcol;
            b[ct] = *(const bf16x8*)(Bbase + n * 272 + ks * 64 + quad * 16);
        }
#pragma unroll
        for (int rt = 0; rt < 2; ++rt)
#pragma unroll
            for (int ct = 0; ct < 8; ++ct)
                acc1[rt][ct] = __builtin_amdgcn_mfma_f32_16x16x32_bf16(
                    a[rt], b[ct], acc1[rt][ct], 0, 0, 0);
    }
    __syncthreads();     // all waves done reading As (xab) and Bs (W1)

    // h (relu + bias, bf16) -> Bs region; W2 tile -> As region
    unsigned short* Hs = (unsigned short*)Bbase;     // pitch 136 ushorts
#pragma unroll
    for (int rt = 0; rt < 2; ++rt)
#pragma unroll
        for (int ct = 0; ct < 8; ++ct) {
            float bb = bias[ct * 16 + mcol];
#pragma unroll
            for (int r = 0; r < 4; ++r) {
                float v = acc1[rt][ct][r] + bb;
                v = v > 0.f ? v : 0.f;
                int orow = wv * 32 + rt * 16 + quad * 4 + r;
                Hs[orow * 136 + ct * 16 + mcol] = (unsigned short)bf16rn(v);
            }
        }
#pragma unroll
    for (int s = 0; s < 3; ++s) {
        int l = tid + s * 256;
        int row = l >> 4, q = l & 15;
        uint4 vb = *(const uint4*)(W2t + (size_t)row * 64 + q * 4);
        *(uint4*)(Abase + row * 272 + q * 16) = vb;
    }
    __syncthreads();

    // ---------------- GEMM2: acc2 = h @ W2t^T ----------------
    f32x4 acc2[2][3];
#pragma unroll
    for (int rt = 0; rt < 2; ++rt)
#pragma unroll
        for (int ct = 0; ct < 3; ++ct) acc2[rt][ct] = (f32x4){0.f, 0.f, 0.f, 0.f};

#pragma unroll
    for (int ks = 0; ks < 4; ++ks) {
        bf16x8 a[2], b[3];
#pragma unroll
        for (int rt = 0; rt < 2; ++rt) {
            int row = wv * 32 + rt * 16 + mcol;
            a[rt] = *(const bf16x8*)(Bbase + row * 272 + ks * 64 + quad * 16);
        }
#pragma unroll
        for (int ct = 0; ct < 3; ++ct) {
            int n = ct * 16 + mcol;
            b[ct] = *(const bf16x8*)(Abase + n * 272 + ks * 64 + quad * 16);
        }
#pragma unroll
        for (int rt = 0; rt < 2; ++rt)
#pragma unroll
            for (int ct = 0; ct < 3; ++ct)
                acc2[rt][ct] = __builtin_amdgcn_mfma_f32_16x16x32_bf16(
                    a[rt], b[ct], acc2[rt][ct], 0, 0, 0);
    }
    __syncthreads();

    // epilogue: scale by dis[row], pack bf16 rows at 56-ushort pitch (112 B)
    unsigned short* Zs = (unsigned short*)(Abase + 16384);  // above W2 (13056 B)
#pragma unroll
    for (int rt = 0; rt < 2; ++rt)
#pragma unroll
        for (int ct = 0; ct < 3; ++ct) {
#pragma unroll
            for (int r = 0; r < 4; ++r) {
                int orow = wv * 32 + rt * 16 + quad * 4 + r;
                float v = acc2[rt][ct][r] * ldis[orow];
                Zs[orow * 56 + ct * 16 + mcol] = (unsigned short)bf16rn(v);
            }
        }
    __syncthreads();

    if (tid < 128) {
        int rr = r0 + tid;
        if (rr < M) {
            const uint4* s4 = (const uint4*)(Abase + 16384 + tid * 112);
            uint4* d4 = (uint4*)(Zb + ((size_t)rr << 5));   // pitch 32 uints
#pragma unroll
            for (int q = 0; q < 5; ++q) d4[q] = s4[q];
        }
    }
}

// ---- gather layer 2: out[c] = b2 + dis[c] * (sum_r zb[r] + zb[c]) ---------
// Half-wave per edge stream; 16 edges in flight (8 per half).
// zb pitch = 32 uints (128 B): one aligned cache line per random row.
__global__ __launch_bounds__(256) void k_gather2(const unsigned* __restrict__ zb,
                                                 const int* __restrict__ rowptr,
                                                 const int* __restrict__ pair,
                                                 const float* __restrict__ dis,
                                                 const float* __restrict__ b2,
                                                 float* __restrict__ out, int N) {
    int gw = (blockIdx.x * 256 + threadIdx.x) >> 6;
    int lane = threadIdx.x & 63;
    if (gw >= N) return;
    int sub = lane >> 5;
    int sl  = lane & 31;
    int f   = (sl < 20) ? sl : 19;

    float2 acc = make_float2(0.f, 0.f);
    float dv = dis[gw];
    if (sub == 0) {                       // self term (rows pre-scaled by dis)
        unsigned u = zb[((size_t)gw << 5) + f];
        acc.x = bf_lo(u); acc.y = bf_hi(u);
    }

    int j = rowptr[gw], je = rowptr[gw + 1];
    for (; j + 15 < je; j += 16) {
        int rA = pair[j + sub];
        int rB = pair[j + 2 + sub];
        int rC = pair[j + 4 + sub];
        int rD = pair[j + 6 + sub];
        int rE = pair[j + 8 + sub];
        int rF = pair[j + 10 + sub];
        int rG = pair[j + 12 + sub];
        int rH = pair[j + 14 + sub];
        unsigned uA = zb[((size_t)rA << 5) + f];
        unsigned uB = zb[((size_t)rB << 5) + f];
        unsigned uC = zb[((size_t)rC << 5) + f];
        unsigned uD = zb[((size_t)rD << 5) + f];
        unsigned uE = zb[((size_t)rE << 5) + f];
        unsigned uF = zb[((size_t)rF << 5) + f];
        unsigned uG = zb[((size_t)rG << 5) + f];
        unsigned uH = zb[((size_t)rH << 5) + f];
        acc.x += bf_lo(uA); acc.y += bf_hi(uA);
        acc.x += bf_lo(uB); acc.y += bf_hi(uB);
        acc.x += bf_lo(uC); acc.y += bf_hi(uC);
        acc.x += bf_lo(uD); acc.y += bf_hi(uD);
        acc.x += bf_lo(uE); acc.y += bf_hi(uE);
        acc.x += bf_lo(uF); acc.y += bf_hi(uF);
        acc.x += bf_lo(uG); acc.y += bf_hi(uG);
        acc.x += bf_lo(uH); acc.y += bf_hi(uH);
    }
    for (; j + 7 < je; j += 8) {
        int rA = pair[j + sub];
        int rB = pair[j + 2 + sub];
        int rC = pair[j + 4 + sub];
        int rD = pair[j + 6 + sub];
        unsigned uA = zb[((size_t)rA << 5) + f];
        unsigned uB = zb[((size_t)rB << 5) + f];
        unsigned uC = zb[((size_t)rC << 5) + f];
        unsigned uD = zb[((size_t)rD << 5) + f];
        acc.x += bf_lo(uA); acc.y += bf_hi(uA);
        acc.x += bf_lo(uB); acc.y += bf_hi(uB);
        acc.x += bf_lo(uC); acc.y += bf_hi(uC);
        acc.x += bf_lo(uD); acc.y += bf_hi(uD);
    }
    for (; j + 3 < je; j += 4) {
        int rA = pair[j + sub];
        int rB = pair[j + 2 + sub];
        unsigned uA = zb[((size_t)rA << 5) + f];
        unsigned uB = zb[((size_t)rB << 5) + f];
        acc.x += bf_lo(uA); acc.y += bf_hi(uA);
        acc.x += bf_lo(uB); acc.y += bf_hi(uB);
    }
    for (; j + 1 < je; j += 2) {
        unsigned u = zb[((size_t)pair[j + sub] << 5) + f];
        acc.x += bf_lo(u); acc.y += bf_hi(u);
    }
    if (j < je && sub == 0) {
        unsigned u = zb[((size_t)pair[j] << 5) + f];
        acc.x += bf_lo(u); acc.y += bf_hi(u);
    }

    float bx = __shfl(acc.x, sl + 32, 64);
    float by = __shfl(acc.y, sl + 32, 64);
    if (sub == 0 && sl < 20) {
        float2 bias = ((const float2*)b2)[sl];
        float2 res = make_float2((acc.x + bx) * dv + bias.x,
                                 (acc.y + by) * dv + bias.y);
        ((float2*)(out + (size_t)gw * 40))[sl] = res;
    }
}

// ---------------------------------------------------------------------------
extern "C" void kernel_launch(void* const* d_in, const int* in_sizes, int n_in,
                              void* d_out, int out_size, void* d_ws, size_t ws_size,
                              hipStream_t stream) {
    const float* x  = (const float*)d_in[0];
    const int*   ei = (const int*)d_in[1];
    const float* W1 = (const float*)d_in[2];
    const float* b1 = (const float*)d_in[3];
    const float* W2 = (const float*)d_in[4];
    const float* b2 = (const float*)d_in[5];
    float* out = (float*)d_out;

    const int N = in_sizes[0] / 128;
    const int E = in_sizes[1] / 2;
    const int* row = ei;        // sources
    const int* col = ei + E;    // targets

    const int Np = (N + 255) & ~255;
    const int nbuck = (N + (1 << FB_SHIFT) - 1) >> FB_SHIFT;   // <= 256

    // workspace layout (4-byte units)
    int*      rowptr = (int*)d_ws;                       // Np + 256
    int*      btot   = rowptr + Np + 256;                // 256
    int*      bbase  = btot + 256;                       // 320 (257 used)
    int*      bcur   = bbase + 320;                      // 256
    float*    dis    = (float*)(bcur + 256);             // Np
    unsigned* Wt     = (unsigned*)(dis + Np);            // 8192 (W1t bf16)
    unsigned* W2t    = Wt + 8192;                        // 3072 (W2t bf16, 48 rows)
    int*      pair   = (int*)(W2t + 3072);               // E ints (src index only)
    unsigned* xb     = (unsigned*)(pair + E);            // N*64 (bf16 x*dis)
    unsigned* xab    = xb + (size_t)N * 64;              // N*64 (bf16 A*x)
    unsigned* zb     = xab + (size_t)N * 64;             // N*32 (bf16 z*dis, padded)
    unsigned* bins   = (unsigned*)xab;  // alias: dead before k_gather1 writes xab

    // bucket histogram -> bucket scan (+W cvt) -> CSC build
    hipMemsetAsync(btot, 0, 256 * sizeof(int), stream);
    k_bcount<<<(E + 4095) / 4096, 512, 0, stream>>>(col, btot, E);
    k_bscanw<<<45, 256, 0, stream>>>(btot, bbase, bcur, W1, W2, Wt, W2t);
    k_binfill<<<(E + 4095) / 4096, 512, 0, stream>>>(row, col, bcur, bins, E);
    k_fill2<<<nbuck, 1024, 0, stream>>>(bins, bbase, rowptr, dis, pair, N);

    // x conversion (full grid, reads dis)
    k_cvtx<<<(N * 32 + 255) / 256, 256, 0, stream>>>(x, dis, xb, N * 32);

    // layer 1 gather: xab = bf16(A x)
    k_gather1<<<(N + 3) / 4, 256, 0, stream>>>(xb, rowptr, pair, dis, xab, N);

    // fused GEMMs: zb = bf16((relu(xab@W1+b1) @ W2) * dis)   [MFMA]
    k_gemm12<<<(N + 127) / 128, 256, 0, stream>>>(xab, Wt, W2t, b1, dis, zb, N);

    // layer 2 gather: out = b2 + dis*(sum zb)
    k_gather2<<<(N + 3) / 4, 256, 0, stream>>>(zb, rowptr, pair, dis, b2, out, N);
}

// Round 8
// 262.040 us; speedup vs baseline: 1.0640x; 1.0420x over previous
//
#include <hip/hip_runtime.h>
#include <hip/hip_bf16.h>

// ---------------------------------------------------------------------------
// 2-layer GCN, atomic-free CSC gather, bf16 payloads + bf16 MFMA GEMMs.
// dis[] is folded into the gathered payloads (xb = x*dis, zb = z*dis), so
// edge records are source-index-only (4 B). Aggregation at target c:
//   A·v|_c = dis[c] * (sum_r payload[r] + payload[c])
// Layer 1: h = relu((A x) @ W1 + b1)   [reassociated]
// Layer 2: out = A (h @ W2) + b2
//
// R1: LDS-aggregated bucket histogram replaces 1.6M global atomics.
// R3: gather1 at compulsory-miss floor (FETCH ~ 8 XCD x 22 MB distinct
// sources = 93% of 190 MB); GEMM1+GEMM2 fused (k_gemm12).
// R5: build chain widened (fill2 1024 thr, binfill 512 thr).
// R7: zb pad was neutral (gather2 latency-bound, zb L2-resident) — kept.
// R8: SLAB buckets (16384-entry fixed slabs, base = b<<14): k_bcount and
// k_bscanw DELETED (no global histogram/scan needed); binfill allocates
// into slabs via bcur atomics; fill2 emits per-node int2 (start,end)
// ranges (rpse). W cvt = tail blocks on binfill. 10 -> 7 dispatches.
// ---------------------------------------------------------------------------

#define FB_SHIFT 9              // 512 nodes per bucket; r<2^17 packs with c_local
#define SLAB_SHIFT 14           // 16384 edge slots per bucket slab (~1.9x max)

__device__ __forceinline__ unsigned bf16rn(float f) {
    unsigned x = __float_as_uint(f);
    unsigned r = ((x >> 16) & 1u) + 0x7fffu;   // RNE
    return (x + r) >> 16;
}
__device__ __forceinline__ float bf_lo(unsigned u) { return __uint_as_float(u << 16); }
__device__ __forceinline__ float bf_hi(unsigned u) { return __uint_as_float(u & 0xffff0000u); }

typedef __bf16 bf16x8 __attribute__((ext_vector_type(8)));
typedef float  f32x4  __attribute__((ext_vector_type(4)));

// ---- multisplit: bin edges by target bucket into fixed slabs --------------
// Edge blocks (blockIdx < nEB): pack (r<<9 | c_local), stage in LDS sorted
// by bucket, allocate slab space via one bcur atomic per bucket, flush.
// Tail blocks (blockIdx >= nEB): W1/W2 -> transposed bf16 (no deps).
__global__ __launch_bounds__(512) void k_binfill(const int* __restrict__ row,
                                                 const int* __restrict__ col,
                                                 int* __restrict__ bcur,
                                                 unsigned* __restrict__ bins, int E,
                                                 int nEB,
                                                 const float* __restrict__ W1,
                                                 const float* __restrict__ W2,
                                                 unsigned* __restrict__ Wt,
                                                 unsigned* __restrict__ W2t) {
    const int tid = threadIdx.x;

    if (blockIdx.x >= nEB) {            // ---- W-conversion tail blocks ----
        int w = (blockIdx.x - nEB) * 512 + tid;   // 0..11263
        if (w < 8192) {
            int n = w >> 6, kk = (w & 63) * 2;
            unsigned lo = bf16rn(W1[(size_t)kk * 128 + n]);
            unsigned hi = bf16rn(W1[(size_t)(kk + 1) * 128 + n]);
            Wt[w] = lo | (hi << 16);
        } else if (w < 8192 + 3072) {
            int u = w - 8192;
            int n = u >> 6, kk = (u & 63) * 2;
            unsigned lo = 0, hi = 0;
            if (n < 40) {
                lo = bf16rn(W2[(size_t)kk * 40 + n]);
                hi = bf16rn(W2[(size_t)(kk + 1) * 40 + n]);
            }
            W2t[u] = lo | (hi << 16);
        }
        return;
    }

    __shared__ int hist[256];
    __shared__ int scn[256];
    __shared__ int gbase[256];
    __shared__ int rcnt[256];
    __shared__ unsigned stage[4096];
    __shared__ unsigned char bkts[4096];

    const int base = blockIdx.x * 4096;

    if (tid < 256) { hist[tid] = 0; rcnt[tid] = 0; }
    __syncthreads();

    unsigned mypk[8];
    int      myb[8];
#pragma unroll
    for (int k = 0; k < 8; ++k) {
        int e = base + k * 512 + tid;
        if (e < E) {
            int r = row[e], c = col[e];
            int b = c >> FB_SHIFT;
            mypk[k] = ((unsigned)r << FB_SHIFT) | (unsigned)(c & ((1 << FB_SHIFT) - 1));
            myb[k] = b;
            atomicAdd(&hist[b], 1);
        } else {
            myb[k] = -1;
        }
    }
    __syncthreads();

    int v = 0;
    if (tid < 256) { v = hist[tid]; scn[tid] = v; }
    __syncthreads();
#pragma unroll
    for (int off = 1; off < 256; off <<= 1) {
        int t = (tid >= off && tid < 256) ? scn[tid - off] : 0;
        __syncthreads();
        if (tid < 256) scn[tid] += t;
        __syncthreads();
    }
    if (tid < 256) {
        int excl = scn[tid] - v;
        scn[tid] = excl;
    }
    __syncthreads();

#pragma unroll
    for (int k = 0; k < 8; ++k) {
        int b = myb[k];
        if (b >= 0) {
            int slot = scn[b] + atomicAdd(&rcnt[b], 1);
            stage[slot] = mypk[k];
            bkts[slot] = (unsigned char)b;
        }
    }

    if (tid < 256 && hist[tid] > 0) gbase[tid] = atomicAdd(&bcur[tid], hist[tid]);
    __syncthreads();

    int total = scn[255] + hist[255];
    const int cap = 1 << SLAB_SHIFT;
    for (int s = tid; s < total; s += 512) {
        unsigned u = stage[s];
        int b = bkts[s];
        int off = gbase[b] + (s - scn[b]);
        if (off < cap)                              // clamp (pathological only)
            bins[((size_t)b << SLAB_SHIFT) + off] = u;
    }
}

// ---- per-bucket: degree count + local scan + scatter; emits rpse + dis ----
__global__ __launch_bounds__(1024) void k_fill2(const unsigned* __restrict__ bins,
                                                const int* __restrict__ bcur,
                                                int2* __restrict__ rpse,
                                                float* __restrict__ dis,
                                                int* __restrict__ pair, int N) {
    __shared__ int cnt[512];
    __shared__ int lcur[512];
    __shared__ int ssum[256];
    const int tid = threadIdx.x;
    const int b = blockIdx.x;
    const int n0 = b << FB_SHIFT;
    const int start = b << SLAB_SHIFT;
    int count = bcur[b];
    if (count > (1 << SLAB_SHIFT)) count = 1 << SLAB_SHIFT;
    const int end = start + count;

    if (tid < 512) cnt[tid] = 0;
    __syncthreads();

    for (int i = start + tid; i < end; i += 1024)
        atomicAdd(&cnt[bins[i] & ((1 << FB_SHIFT) - 1)], 1);
    __syncthreads();

    int c0 = 0, c1 = 0, vsum = 0;
    if (tid < 256) {
        c0 = cnt[2 * tid]; c1 = cnt[2 * tid + 1];
        vsum = c0 + c1;
        ssum[tid] = vsum;
    }
    __syncthreads();
#pragma unroll
    for (int off = 1; off < 256; off <<= 1) {
        int u = (tid >= off && tid < 256) ? ssum[tid - off] : 0;
        __syncthreads();
        if (tid < 256) ssum[tid] += u;
        __syncthreads();
    }
    if (tid < 256) {
        int e0 = start + ssum[tid] - vsum;
        int e1 = e0 + c0;
        lcur[2 * tid] = e0;
        lcur[2 * tid + 1] = e1;
        int node0 = n0 + 2 * tid;
        int node1 = node0 + 1;
        if (node0 < N) {
            rpse[node0] = make_int2(e0, e1);
            dis[node0] = rsqrtf((float)(c0 + 1));   // +1 self-loop
        }
        if (node1 < N) {
            rpse[node1] = make_int2(e1, e1 + c1);
            dis[node1] = rsqrtf((float)(c1 + 1));
        }
    }
    __syncthreads();

    for (int i = start + tid; i < end; i += 1024) {
        unsigned u = bins[i];
        int pos = atomicAdd(&lcur[u & ((1 << FB_SHIFT) - 1)], 1);
        pair[pos] = (int)(u >> FB_SHIFT);
    }
}

// ---- x -> xb = bf16x2(x * dis), full-grid streaming, float4/lane ----------
__global__ __launch_bounds__(256) void k_cvtx(const float* __restrict__ x,
                                              const float* __restrict__ dis,
                                              unsigned* __restrict__ xb, int n32) {
    int i = blockIdx.x * 256 + threadIdx.x;
    if (i >= n32) return;
    float4 v = ((const float4*)x)[i];
    float d = dis[i >> 5];
    uint2 o;
    o.x = bf16rn(v.x * d) | (bf16rn(v.y * d) << 16);
    o.y = bf16rn(v.z * d) | (bf16rn(v.w * d) << 16);
    ((uint2*)xb)[i] = o;
}

// ---- gather layer 1: xab[c] = bf16(dis[c] * (sum_r xb[r] + xb[c])) --------
// Wave per node; index-only pair records; 8 gathers in flight. At the
// compulsory-miss floor (FETCH ~ 8 XCD x 22 MB distinct source rows).
__global__ __launch_bounds__(256) void k_gather1(const unsigned* __restrict__ xb,
                                                 const int2* __restrict__ rpse,
                                                 const int* __restrict__ pair,
                                                 const float* __restrict__ dis,
                                                 unsigned* __restrict__ xab, int N) {
    int gw = (blockIdx.x * 256 + threadIdx.x) >> 6;
    int lane = threadIdx.x & 63;
    if (gw >= N) return;
    float dv = dis[gw];
    unsigned us = xb[(size_t)gw * 64 + lane];
    float2 acc = make_float2(bf_lo(us), bf_hi(us));   // self term (rows pre-scaled)
    int2 rp = rpse[gw];
    int j = rp.x, je = rp.y;

    for (; j + 7 < je; j += 8) {
        int r0 = pair[j],     r1 = pair[j + 1], r2 = pair[j + 2], r3 = pair[j + 3];
        int r4 = pair[j + 4], r5 = pair[j + 5], r6 = pair[j + 6], r7 = pair[j + 7];
        unsigned a0 = xb[(size_t)r0 * 64 + lane];
        unsigned a1 = xb[(size_t)r1 * 64 + lane];
        unsigned a2 = xb[(size_t)r2 * 64 + lane];
        unsigned a3 = xb[(size_t)r3 * 64 + lane];
        unsigned a4 = xb[(size_t)r4 * 64 + lane];
        unsigned a5 = xb[(size_t)r5 * 64 + lane];
        unsigned a6 = xb[(size_t)r6 * 64 + lane];
        unsigned a7 = xb[(size_t)r7 * 64 + lane];
        acc.x += bf_lo(a0); acc.y += bf_hi(a0);
        acc.x += bf_lo(a1); acc.y += bf_hi(a1);
        acc.x += bf_lo(a2); acc.y += bf_hi(a2);
        acc.x += bf_lo(a3); acc.y += bf_hi(a3);
        acc.x += bf_lo(a4); acc.y += bf_hi(a4);
        acc.x += bf_lo(a5); acc.y += bf_hi(a5);
        acc.x += bf_lo(a6); acc.y += bf_hi(a6);
        acc.x += bf_lo(a7); acc.y += bf_hi(a7);
    }
    for (; j + 3 < je; j += 4) {
        int r0 = pair[j], r1 = pair[j + 1], r2 = pair[j + 2], r3 = pair[j + 3];
        unsigned a0 = xb[(size_t)r0 * 64 + lane];
        unsigned a1 = xb[(size_t)r1 * 64 + lane];
        unsigned a2 = xb[(size_t)r2 * 64 + lane];
        unsigned a3 = xb[(size_t)r3 * 64 + lane];
        acc.x += bf_lo(a0); acc.y += bf_hi(a0);
        acc.x += bf_lo(a1); acc.y += bf_hi(a1);
        acc.x += bf_lo(a2); acc.y += bf_hi(a2);
        acc.x += bf_lo(a3); acc.y += bf_hi(a3);
    }
    for (; j < je; ++j) {
        unsigned a0 = xb[(size_t)pair[j] * 64 + lane];
        acc.x += bf_lo(a0); acc.y += bf_hi(a0);
    }
    xab[(size_t)gw * 64 + lane] = bf16rn(dv * acc.x) | (bf16rn(dv * acc.y) << 16);
}

// ---- fused GEMM1+GEMM2 (MFMA bf16) ----------------------------------------
// h = relu(xab @ W1t^T + b1)  (h kept in LDS, never hits global)
// Zb[M, pitch 32] = bf16( (h @ W2t^T) * dis[row] )  (20 uints used, 12 pad)
__global__ __launch_bounds__(256) void k_gemm12(const unsigned* __restrict__ Ab,
                                                const unsigned* __restrict__ Wt,
                                                const unsigned* __restrict__ W2t,
                                                const float* __restrict__ bias,
                                                const float* __restrict__ dis,
                                                unsigned* __restrict__ Zb, int M) {
    __shared__ char smem[70144];            // 34816 + 34816 + 512 (ldis)
    char* Abase = smem;
    char* Bbase = smem + 34816;
    float* ldis = (float*)(smem + 69632);

    const int tid = threadIdx.x;
    const int r0 = blockIdx.x * 128;

#pragma unroll
    for (int s = 0; s < 8; ++s) {
        int l = tid + s * 256;
        int row = l >> 4, q = l & 15;
        uint4 va = *(const uint4*)(Ab + (size_t)(r0 + row) * 64 + q * 4);
        *(uint4*)(Abase + row * 272 + q * 16) = va;
        uint4 vb = *(const uint4*)(Wt + (size_t)row * 64 + q * 4);
        *(uint4*)(Bbase + row * 272 + q * 16) = vb;
    }
    if (tid < 128) {
        int rr = r0 + tid;
        ldis[tid] = (rr < M) ? dis[rr] : 0.f;
    }
    __syncthreads();

    const int wv = tid >> 6, lane = tid & 63;
    const int quad = lane >> 4, mcol = lane & 15;

    // ---------------- GEMM1: acc1 = xab @ W1t^T ----------------
    f32x4 acc1[2][8];
#pragma unroll
    for (int rt = 0; rt < 2; ++rt)
#pragma unroll
        for (int ct = 0; ct < 8; ++ct) acc1[rt][ct] = (f32x4){0.f, 0.f, 0.f, 0.f};

#pragma unroll
    for (int ks = 0; ks < 4; ++ks) {
        bf16x8 a[2], b[8];
#pragma unroll
        for (int rt = 0; rt < 2; ++rt) {
            int row = wv * 32 + rt * 16 + mcol;
            a[rt] = *(const bf16x8*)(Abase + row * 272 + ks * 64 + quad * 16);
        }
#pragma unroll
        for (int ct = 0; ct < 8; ++ct) {
            int n = ct * 16 + mcol;
            b[ct] = *(const bf16x8*)(Bbase + n * 272 + ks * 64 + quad * 16);
        }
#pragma unroll
        for (int rt = 0; rt < 2; ++rt)
#pragma unroll
            for (int ct = 0; ct < 8; ++ct)
                acc1[rt][ct] = __builtin_amdgcn_mfma_f32_16x16x32_bf16(
                    a[rt], b[ct], acc1[rt][ct], 0, 0, 0);
    }
    __syncthreads();     // all waves done reading As (xab) and Bs (W1)

    // h (relu + bias, bf16) -> Bs region; W2 tile -> As region
    unsigned short* Hs = (unsigned short*)Bbase;     // pitch 136 ushorts
#pragma unroll
    for (int rt = 0; rt < 2; ++rt)
#pragma unroll
        for (int ct = 0; ct < 8; ++ct) {
            float bb = bias[ct * 16 + mcol];
#pragma unroll
            for (int r = 0; r < 4; ++r) {
                float v = acc1[rt][ct][r] + bb;
                v = v > 0.f ? v : 0.f;
                int orow = wv * 32 + rt * 16 + quad * 4 + r;
                Hs[orow * 136 + ct * 16 + mcol] = (unsigned short)bf16rn(v);
            }
        }
#pragma unroll
    for (int s = 0; s < 3; ++s) {
        int l = tid + s * 256;
        int row = l >> 4, q = l & 15;
        uint4 vb = *(const uint4*)(W2t + (size_t)row * 64 + q * 4);
        *(uint4*)(Abase + row * 272 + q * 16) = vb;
    }
    __syncthreads();

    // ---------------- GEMM2: acc2 = h @ W2t^T ----------------
    f32x4 acc2[2][3];
#pragma unroll
    for (int rt = 0; rt < 2; ++rt)
#pragma unroll
        for (int ct = 0; ct < 3; ++ct) acc2[rt][ct] = (f32x4){0.f, 0.f, 0.f, 0.f};

#pragma unroll
    for (int ks = 0; ks < 4; ++ks) {
        bf16x8 a[2], b[3];
#pragma unroll
        for (int rt = 0; rt < 2; ++rt) {
            int row = wv * 32 + rt * 16 + mcol;
            a[rt] = *(const bf16x8*)(Bbase + row * 272 + ks * 64 + quad * 16);
        }
#pragma unroll
        for (int ct = 0; ct < 3; ++ct) {
            int n = ct * 16 + mcol;
            b[ct] = *(const bf16x8*)(Abase + n * 272 + ks * 64 + quad * 16);
        }
#pragma unroll
        for (int rt = 0; rt < 2; ++rt)
#pragma unroll
            for (int ct = 0; ct < 3; ++ct)
                acc2[rt][ct] = __builtin_amdgcn_mfma_f32_16x16x32_bf16(
                    a[rt], b[ct], acc2[rt][ct], 0, 0, 0);
    }
    __syncthreads();

    // epilogue: scale by dis[row], pack bf16 rows at 56-ushort pitch (112 B)
    unsigned short* Zs = (unsigned short*)(Abase + 16384);  // above W2 (13056 B)
#pragma unroll
    for (int rt = 0; rt < 2; ++rt)
#pragma unroll
        for (int ct = 0; ct < 3; ++ct) {
#pragma unroll
            for (int r = 0; r < 4; ++r) {
                int orow = wv * 32 + rt * 16 + quad * 4 + r;
                float v = acc2[rt][ct][r] * ldis[orow];
                Zs[orow * 56 + ct * 16 + mcol] = (unsigned short)bf16rn(v);
            }
        }
    __syncthreads();

    if (tid < 128) {
        int rr = r0 + tid;
        if (rr < M) {
            const uint4* s4 = (const uint4*)(Abase + 16384 + tid * 112);
            uint4* d4 = (uint4*)(Zb + ((size_t)rr << 5));   // pitch 32 uints
#pragma unroll
            for (int q = 0; q < 5; ++q) d4[q] = s4[q];
        }
    }
}

// ---- gather layer 2: out[c] = b2 + dis[c] * (sum_r zb[r] + zb[c]) ---------
// Half-wave per edge stream; 16 edges in flight (8 per half).
// zb pitch = 32 uints (128 B): one aligned cache line per random row.
__global__ __launch_bounds__(256) void k_gather2(const unsigned* __restrict__ zb,
                                                 const int2* __restrict__ rpse,
                                                 const int* __restrict__ pair,
                                                 const float* __restrict__ dis,
                                                 const float* __restrict__ b2,
                                                 float* __restrict__ out, int N) {
    int gw = (blockIdx.x * 256 + threadIdx.x) >> 6;
    int lane = threadIdx.x & 63;
    if (gw >= N) return;
    int sub = lane >> 5;
    int sl  = lane & 31;
    int f   = (sl < 20) ? sl : 19;

    float2 acc = make_float2(0.f, 0.f);
    float dv = dis[gw];
    if (sub == 0) {                       // self term (rows pre-scaled by dis)
        unsigned u = zb[((size_t)gw << 5) + f];
        acc.x = bf_lo(u); acc.y = bf_hi(u);
    }

    int2 rp = rpse[gw];
    int j = rp.x, je = rp.y;
    for (; j + 15 < je; j += 16) {
        int rA = pair[j + sub];
        int rB = pair[j + 2 + sub];
        int rC = pair[j + 4 + sub];
        int rD = pair[j + 6 + sub];
        int rE = pair[j + 8 + sub];
        int rF = pair[j + 10 + sub];
        int rG = pair[j + 12 + sub];
        int rH = pair[j + 14 + sub];
        unsigned uA = zb[((size_t)rA << 5) + f];
        unsigned uB = zb[((size_t)rB << 5) + f];
        unsigned uC = zb[((size_t)rC << 5) + f];
        unsigned uD = zb[((size_t)rD << 5) + f];
        unsigned uE = zb[((size_t)rE << 5) + f];
        unsigned uF = zb[((size_t)rF << 5) + f];
        unsigned uG = zb[((size_t)rG << 5) + f];
        unsigned uH = zb[((size_t)rH << 5) + f];
        acc.x += bf_lo(uA); acc.y += bf_hi(uA);
        acc.x += bf_lo(uB); acc.y += bf_hi(uB);
        acc.x += bf_lo(uC); acc.y += bf_hi(uC);
        acc.x += bf_lo(uD); acc.y += bf_hi(uD);
        acc.x += bf_lo(uE); acc.y += bf_hi(uE);
        acc.x += bf_lo(uF); acc.y += bf_hi(uF);
        acc.x += bf_lo(uG); acc.y += bf_hi(uG);
        acc.x += bf_lo(uH); acc.y += bf_hi(uH);
    }
    for (; j + 7 < je; j += 8) {
        int rA = pair[j + sub];
        int rB = pair[j + 2 + sub];
        int rC = pair[j + 4 + sub];
        int rD = pair[j + 6 + sub];
        unsigned uA = zb[((size_t)rA << 5) + f];
        unsigned uB = zb[((size_t)rB << 5) + f];
        unsigned uC = zb[((size_t)rC << 5) + f];
        unsigned uD = zb[((size_t)rD << 5) + f];
        acc.x += bf_lo(uA); acc.y += bf_hi(uA);
        acc.x += bf_lo(uB); acc.y += bf_hi(uB);
        acc.x += bf_lo(uC); acc.y += bf_hi(uC);
        acc.x += bf_lo(uD); acc.y += bf_hi(uD);
    }
    for (; j + 3 < je; j += 4) {
        int rA = pair[j + sub];
        int rB = pair[j + 2 + sub];
        unsigned uA = zb[((size_t)rA << 5) + f];
        unsigned uB = zb[((size_t)rB << 5) + f];
        acc.x += bf_lo(uA); acc.y += bf_hi(uA);
        acc.x += bf_lo(uB); acc.y += bf_hi(uB);
    }
    for (; j + 1 < je; j += 2) {
        unsigned u = zb[((size_t)pair[j + sub] << 5) + f];
        acc.x += bf_lo(u); acc.y += bf_hi(u);
    }
    if (j < je && sub == 0) {
        unsigned u = zb[((size_t)pair[j] << 5) + f];
        acc.x += bf_lo(u); acc.y += bf_hi(u);
    }

    float bx = __shfl(acc.x, sl + 32, 64);
    float by = __shfl(acc.y, sl + 32, 64);
    if (sub == 0 && sl < 20) {
        float2 bias = ((const float2*)b2)[sl];
        float2 res = make_float2((acc.x + bx) * dv + bias.x,
                                 (acc.y + by) * dv + bias.y);
        ((float2*)(out + (size_t)gw * 40))[sl] = res;
    }
}

// ---------------------------------------------------------------------------
extern "C" void kernel_launch(void* const* d_in, const int* in_sizes, int n_in,
                              void* d_out, int out_size, void* d_ws, size_t ws_size,
                              hipStream_t stream) {
    const float* x  = (const float*)d_in[0];
    const int*   ei = (const int*)d_in[1];
    const float* W1 = (const float*)d_in[2];
    const float* b1 = (const float*)d_in[3];
    const float* W2 = (const float*)d_in[4];
    const float* b2 = (const float*)d_in[5];
    float* out = (float*)d_out;

    const int N = in_sizes[0] / 128;
    const int E = in_sizes[1] / 2;
    const int* row = ei;        // sources
    const int* col = ei + E;    // targets

    const int Np = (N + 255) & ~255;
    const int nbuck = (N + (1 << FB_SHIFT) - 1) >> FB_SHIFT;   // <= 256
    const int nEB = (E + 4095) / 4096;

    // workspace layout (4-byte units), ~82 MB total
    int*      bcur   = (int*)d_ws;                       // 256
    int2*     rpse   = (int2*)(bcur + 256);              // Np int2 (2*Np ints)
    float*    dis    = (float*)(rpse + Np);              // Np
    unsigned* Wt     = (unsigned*)(dis + Np);            // 8192 (W1t bf16)
    unsigned* W2t    = Wt + 8192;                        // 3072 (W2t bf16, 48 rows)
    int*      pair   = (int*)(W2t + 3072);               // 256<<14 slabbed
    unsigned* xb     = (unsigned*)(pair + ((size_t)256 << SLAB_SHIFT)); // N*64
    unsigned* xab    = xb + (size_t)N * 64;              // N*64 (bf16 A*x)
    unsigned* zb     = xab + (size_t)N * 64;             // N*32 (bf16 z*dis, padded)
    unsigned* bins   = (unsigned*)xab;  // alias: slabbed, dead before gather1

    // slab-bucketed CSC build (no global histogram/scan needed)
    hipMemsetAsync(bcur, 0, 256 * sizeof(int), stream);
    k_binfill<<<nEB + 22, 512, 0, stream>>>(row, col, bcur, bins, E, nEB,
                                            W1, W2, Wt, W2t);
    k_fill2<<<nbuck, 1024, 0, stream>>>(bins, bcur, rpse, dis, pair, N);

    // x conversion (full grid, reads dis)
    k_cvtx<<<(N * 32 + 255) / 256, 256, 0, stream>>>(x, dis, xb, N * 32);

    // layer 1 gather: xab = bf16(A x)
    k_gather1<<<(N + 3) / 4, 256, 0, stream>>>(xb, rpse, pair, dis, xab, N);

    // fused GEMMs: zb = bf16((relu(xab@W1+b1) @ W2) * dis)   [MFMA]
    k_gemm12<<<(N + 127) / 128, 256, 0, stream>>>(xab, Wt, W2t, b1, dis, zb, N);

    // layer 2 gather: out = b2 + dis*(sum zb)
    k_gather2<<<(N + 3) / 4, 256, 0, stream>>>(zb, rpse, pair, dis, b2, out, N);
}